// Round 2
// baseline (843.771 us; speedup 1.0000x reference)
//
#include <hip/hip_runtime.h>

#define NN 100000
#define DD 128

__device__ __forceinline__ float bf2f(unsigned short u) {
    union { unsigned int i; float f; } v;
    v.i = ((unsigned int)u) << 16;
    return v.f;
}

__device__ __forceinline__ unsigned short f2bf(float f) {
    union { float f; unsigned int i; } v;
    v.f = f;
    unsigned int x = v.i;
    return (unsigned short)((x + 0x7FFFu + ((x >> 16) & 1u)) >> 16);
}

// ---- dtype-generic 4-element loads/stores (fp32 or bf16 storage) ----
__device__ __forceinline__ float4 load4(const float* p, int i4) {
    return ((const float4*)p)[i4];
}
__device__ __forceinline__ float4 load4(const unsigned short* p, int i4) {
    ushort4 v = ((const ushort4*)p)[i4];
    return make_float4(bf2f(v.x), bf2f(v.y), bf2f(v.z), bf2f(v.w));
}
__device__ __forceinline__ void store4(float* p, int i4, float4 v) {
    ((float4*)p)[i4] = v;
}
__device__ __forceinline__ void store4(unsigned short* p, int i4, float4 v) {
    ushort4 o;
    o.x = f2bf(v.x); o.y = f2bf(v.y); o.z = f2bf(v.z); o.w = f2bf(v.w);
    ((ushort4*)p)[i4] = o;
}
__device__ __forceinline__ float2 load2(const float* p, int i2) {
    return ((const float2*)p)[i2];
}
__device__ __forceinline__ float2 load2(const unsigned short* p, int i2) {
    unsigned int v = ((const unsigned int*)p)[i2];
    return make_float2(bf2f((unsigned short)(v & 0xFFFFu)), bf2f((unsigned short)(v >> 16)));
}

__global__ void zero_ints(int* __restrict__ a, int n) {
    int i = blockIdx.x * blockDim.x + threadIdx.x;
    if (i < n) a[i] = 0;
}

// edge_index may arrive as int64 (reference dtype) or int32 (harness contract).
// int64 little-endian with values < 2^31 => every odd int32 word is 0.
__global__ void detect64(const int* __restrict__ ei, int* __restrict__ flag) {
    if (blockIdx.x == 0 && threadIdx.x == 0) {
        int is64 = 1;
        for (int i = 0; i < 128; i++)
            if (ei[2 * i + 1] != 0) { is64 = 0; break; }
        flag[0] = is64;
    }
}

__global__ void count_deg(const int* __restrict__ ei, int E, const int* __restrict__ flag,
                          int* __restrict__ cnt) {
    int e = blockIdx.x * blockDim.x + threadIdx.x;
    if (e >= E) return;
    int d = flag[0] ? ei[2 * (E + e)] : ei[E + e];
    atomicAdd(&cnt[d], 1);
}

// single-block exclusive scan, wave-shuffle based (3 barriers per 1024 chunk)
__global__ void scan_excl(const int* __restrict__ cnt, int N, int* __restrict__ off) {
    __shared__ int wsum[16];
    __shared__ int carry_s;
    int lane = threadIdx.x & 63;
    int wid = threadIdx.x >> 6;
    if (threadIdx.x == 0) carry_s = 0;
    __syncthreads();
    for (int base = 0; base < N; base += 1024) {
        int i = base + threadIdx.x;
        int v = (i < N) ? cnt[i] : 0;
        int s = v;
#pragma unroll
        for (int d = 1; d < 64; d <<= 1) {
            int t = __shfl_up(s, d, 64);
            if (lane >= d) s += t;
        }
        if (lane == 63) wsum[wid] = s;
        __syncthreads();
        int woff = 0;
#pragma unroll
        for (int w = 0; w < 16; w++) woff += (w < wid) ? wsum[w] : 0;
        int incl = carry_s + woff + s;
        if (i < N) off[i] = incl - v;   // exclusive
        __syncthreads();                // all reads of carry_s/wsum done
        if (threadIdx.x == 1023) carry_s = incl;
        __syncthreads();
    }
    if (threadIdx.x == 0) off[N] = carry_s;
}

__global__ void fill_csr(const int* __restrict__ ei, int E, const int* __restrict__ flag,
                         const int* __restrict__ off, int* __restrict__ cur,
                         int* __restrict__ csr) {
    int e = blockIdx.x * blockDim.x + threadIdx.x;
    if (e >= E) return;
    int is64 = flag[0];
    int s = is64 ? ei[2 * e] : ei[e];
    int d = is64 ? ei[2 * (E + e)] : ei[E + e];
    int p = atomicAdd(&cur[d], 1);
    csr[off[d] + p] = s;
}

// one 64-lane wave per node; lane handles 2 consecutive features
template <typename TI, typename TO>
__global__ void aggregate(const TI* __restrict__ feat,
                          const int* __restrict__ off, const int* __restrict__ csr,
                          TO* __restrict__ mean, int N) {
    int node = blockIdx.x * (blockDim.x >> 6) + (threadIdx.x >> 6);
    if (node >= N) return;
    int lane = threadIdx.x & 63;
    int s0 = off[node], s1 = off[node + 1];
    float ax = 0.f, ay = 0.f;
    for (int j = s0; j < s1; j++) {
        int s = csr[j];
        float2 v = load2(feat, s * 64 + lane);
        ax += v.x; ay += v.y;
    }
    float inv = (s1 > s0) ? (1.0f / (float)(s1 - s0)) : 0.0f;
    float2 o = make_float2(ax * inv, ay * inv);
    if constexpr (__is_same(TO, float)) {
        ((float2*)mean)[node * 64 + lane] = o;
    } else {
        unsigned int p = (unsigned int)f2bf(o.x) | ((unsigned int)f2bf(o.y) << 16);
        ((unsigned int*)mean)[node * 64 + lane] = p;
    }
}

// out[n][f] = sum_k A1[n][k]*W1[k][f] + sum_k A2[n][k]*W2[k][f] + bias[f]
// tile: 64 nodes x 128 feats per block; 256 threads; thread = (ty: 8 nodes, tx: 4 feats)
template <typename TA1, typename TA2, typename TO>
__global__ __launch_bounds__(256) void fused_gemm(
    const TA1* __restrict__ A1, const TA2* __restrict__ A2,
    const float* __restrict__ W1, const float* __restrict__ W2,
    const float* __restrict__ bias, TO* __restrict__ out,
    int Arows, int Nlimit, const int* __restrict__ origp) {
    int lim = Nlimit;
    if (origp) lim = min(lim, *origp);   // low int32 word works for int32 or int64
    int n0 = blockIdx.x * 64;
    if (n0 >= lim) return;

    __shared__ float As[32 * 68];   // [k][node], stride 68
    __shared__ float Bs[32 * 128];  // [k][f]

    int tid = threadIdx.x;
    int tx = tid & 31;   // feature group: f = tx*4 .. +3
    int ty = tid >> 5;   // node group: n = n0 + ty*8 .. +7

    float acc[8][4];
#pragma unroll
    for (int i = 0; i < 8; i++)
#pragma unroll
        for (int c = 0; c < 4; c++) acc[i][c] = 0.f;

    for (int phase = 0; phase < 2; phase++) {
        const float* W = phase ? W2 : W1;
        for (int kb = 0; kb < 128; kb += 32) {
            __syncthreads();
            // stage A tile: 64 nodes x 32 k, transposed to As[k][node]
#pragma unroll
            for (int r = 0; r < 2; r++) {
                int s = tid + r * 256;       // 512 slots x 4 elems
                int node = s >> 3, kq = s & 7;
                int gn = n0 + node;
                float4 v = make_float4(0.f, 0.f, 0.f, 0.f);
                if (gn < Arows) {
                    int gidx = gn * 32 + (kb >> 2) + kq;
                    v = phase ? load4(A2, gidx) : load4(A1, gidx);
                }
                As[(kq * 4 + 0) * 68 + node] = v.x;
                As[(kq * 4 + 1) * 68 + node] = v.y;
                As[(kq * 4 + 2) * 68 + node] = v.z;
                As[(kq * 4 + 3) * 68 + node] = v.w;
            }
            // stage W tile: 32 k x 128 f
#pragma unroll
            for (int r = 0; r < 4; r++) {
                int s = tid + r * 256;       // 1024 slots x 4 elems
                int k = s >> 5, f4 = s & 31;
                *((float4*)&Bs[k * 128 + f4 * 4]) = load4(W, (kb + k) * 32 + f4);
            }
            __syncthreads();
#pragma unroll
            for (int k = 0; k < 32; k++) {
                float4 b = *((const float4*)&Bs[k * 128 + tx * 4]);
                float4 a0 = *((const float4*)&As[k * 68 + ty * 8]);
                float4 a1 = *((const float4*)&As[k * 68 + ty * 8 + 4]);
                float a[8] = {a0.x, a0.y, a0.z, a0.w, a1.x, a1.y, a1.z, a1.w};
#pragma unroll
                for (int i = 0; i < 8; i++) {
                    acc[i][0] += a[i] * b.x;
                    acc[i][1] += a[i] * b.y;
                    acc[i][2] += a[i] * b.z;
                    acc[i][3] += a[i] * b.w;
                }
            }
        }
    }

    float4 bb = load4(bias, tx);
#pragma unroll
    for (int i = 0; i < 8; i++) {
        int n = n0 + ty * 8 + i;
        if (n < lim) {
            float4 o = make_float4(acc[i][0] + bb.x, acc[i][1] + bb.y,
                                   acc[i][2] + bb.z, acc[i][3] + bb.w);
            store4(out, n * 32 + tx, o);
        }
    }
}

extern "C" void kernel_launch(void* const* d_in, const int* in_sizes, int n_in,
                              void* d_out, int out_size, void* d_ws, size_t ws_size,
                              hipStream_t stream) {
    const float* x   = (const float*)d_in[0];
    const int*   ei  = (const int*)d_in[1];
    const int*   org = (const int*)d_in[2];
    const float* Wl1 = (const float*)d_in[3];
    const float* bl1 = (const float*)d_in[4];
    const float* Wr1 = (const float*)d_in[5];
    const float* Wl2 = (const float*)d_in[6];
    const float* bl2 = (const float*)d_in[7];
    const float* Wr2 = (const float*)d_in[8];
    float* out = (float*)d_out;

    const int N = NN;
    const int E = in_sizes[1] / 2;

    // workspace layout. mean is always bf16 (small magnitudes -> tiny error);
    // h is fp32 if ws_size permits, else bf16. Deterministic per session.
    size_t szMean = (size_t)N * DD * 2;
    size_t szH32  = (size_t)N * DD * 4;
    size_t szH16  = (size_t)N * DD * 2;
    size_t szMisc = (size_t)N * 4 * 2 + (size_t)(N + 1) * 4 + 16 + (size_t)E * 4;
    bool h_fp32 = ws_size >= szMean + szH32 + szMisc + 1024;

    char* ws = (char*)d_ws;
    unsigned short* mean = (unsigned short*)ws;  ws += szMean;
    char* hbuf = ws;                              ws += (h_fp32 ? szH32 : szH16);
    int* cnt  = (int*)ws;  ws += (size_t)N * 4;   // cnt+cur adjacent: one zeroing pass
    int* cur  = (int*)ws;  ws += (size_t)N * 4;
    int* off  = (int*)ws;  ws += (size_t)(N + 1) * 4;
    int* flag = (int*)ws;  ws += 16;
    int* csr  = (int*)ws;

    // --- build CSR by dst ---
    zero_ints<<<(2 * N + 255) / 256, 256, 0, stream>>>(cnt, 2 * N);
    detect64<<<1, 64, 0, stream>>>(ei, flag);
    count_deg<<<(E + 255) / 256, 256, 0, stream>>>(ei, E, flag, cnt);
    scan_excl<<<1, 1024, 0, stream>>>(cnt, N, off);
    fill_csr<<<(E + 255) / 256, 256, 0, stream>>>(ei, E, flag, off, cur, csr);

    int aggGrid  = (N + 3) / 4;      // 4 waves (nodes) per 256-thread block
    int gemmGrid = (N + 63) / 64;

    if (h_fp32) {
        float* h = (float*)hbuf;
        aggregate<float, unsigned short><<<aggGrid, 256, 0, stream>>>(x, off, csr, mean, N);
        fused_gemm<unsigned short, float, float><<<gemmGrid, 256, 0, stream>>>(
            mean, x, Wl1, Wr1, bl1, h, N, N, nullptr);
        aggregate<float, unsigned short><<<aggGrid, 256, 0, stream>>>(h, off, csr, mean, N);
        fused_gemm<unsigned short, float, float><<<gemmGrid, 256, 0, stream>>>(
            mean, h, Wl2, Wr2, bl2, out, N, N, org);
    } else {
        unsigned short* h = (unsigned short*)hbuf;
        aggregate<float, unsigned short><<<aggGrid, 256, 0, stream>>>(x, off, csr, mean, N);
        fused_gemm<unsigned short, float, unsigned short><<<gemmGrid, 256, 0, stream>>>(
            mean, x, Wl1, Wr1, bl1, h, N, N, nullptr);
        aggregate<unsigned short, unsigned short><<<aggGrid, 256, 0, stream>>>(h, off, csr, mean, N);
        fused_gemm<unsigned short, unsigned short, float><<<gemmGrid, 256, 0, stream>>>(
            mean, h, Wl2, Wr2, bl2, out, N, N, org);
    }
}

// Round 4
// 677.526 us; speedup vs baseline: 1.2454x; 1.2454x over previous
//
#include <hip/hip_runtime.h>

#define NN 100000
#define DD 128

typedef __attribute__((ext_vector_type(8))) short bf16x8;
typedef __attribute__((ext_vector_type(4))) float f32x4;

__device__ __forceinline__ float bf2f(unsigned short u) {
    union { unsigned int i; float f; } v;
    v.i = ((unsigned int)u) << 16;
    return v.f;
}

__device__ __forceinline__ unsigned short f2bf(float f) {
    union { float f; unsigned int i; } v;
    v.f = f;
    unsigned int x = v.i;
    return (unsigned short)((x + 0x7FFFu + ((x >> 16) & 1u)) >> 16);
}

__device__ __forceinline__ float2 load2(const float* p, int i2) {
    return ((const float2*)p)[i2];
}
__device__ __forceinline__ float2 load2(const unsigned short* p, int i2) {
    unsigned int v = ((const unsigned int*)p)[i2];
    return make_float2(bf2f((unsigned short)(v & 0xFFFFu)), bf2f((unsigned short)(v >> 16)));
}

// 8 bf16 elements from bf16 or fp32 storage (for GEMM A staging)
__device__ __forceinline__ bf16x8 load8_bf(const unsigned short* p) {
    return *((const bf16x8*)p);
}
__device__ __forceinline__ bf16x8 load8_bf(const float* p) {
    float4 a = ((const float4*)p)[0];
    float4 b = ((const float4*)p)[1];
    bf16x8 r;
    r[0] = (short)f2bf(a.x); r[1] = (short)f2bf(a.y);
    r[2] = (short)f2bf(a.z); r[3] = (short)f2bf(a.w);
    r[4] = (short)f2bf(b.x); r[5] = (short)f2bf(b.y);
    r[6] = (short)f2bf(b.z); r[7] = (short)f2bf(b.w);
    return r;
}

__global__ void zero_ints(int* __restrict__ a, int n) {
    int i = blockIdx.x * blockDim.x + threadIdx.x;
    if (i < n) a[i] = 0;
}

// one wave; int64 little-endian edges with values < 2^31 => odd words all zero
__global__ void detect64(const int* __restrict__ ei, int* __restrict__ flag) {
    int ok = (ei[2 * threadIdx.x + 1] == 0);
    int all = __all(ok);
    if (threadIdx.x == 0) flag[0] = all;
}

__global__ void count_deg(const int* __restrict__ ei, int E, const int* __restrict__ flag,
                          int* __restrict__ cnt) {
    int e = blockIdx.x * blockDim.x + threadIdx.x;
    if (e >= E) return;
    int d = flag[0] ? ei[2 * (E + e)] : ei[E + e];
    atomicAdd(&cnt[d], 1);
}

// ---- multi-block scan (3 passes) ----
__global__ void scan1(const int* __restrict__ cnt, int N, int* __restrict__ off,
                      int* __restrict__ bsum) {
    __shared__ int wsum[16];
    int i = blockIdx.x * 1024 + threadIdx.x;
    int lane = threadIdx.x & 63, wid = threadIdx.x >> 6;
    int v = (i < N) ? cnt[i] : 0;
    int s = v;
#pragma unroll
    for (int d = 1; d < 64; d <<= 1) {
        int t = __shfl_up(s, d, 64);
        if (lane >= d) s += t;
    }
    if (lane == 63) wsum[wid] = s;
    __syncthreads();
    int woff = 0;
#pragma unroll
    for (int w = 0; w < 16; w++) woff += (w < wid) ? wsum[w] : 0;
    if (i < N) off[i] = woff + s - v;   // block-local exclusive
    if (threadIdx.x == 1023) bsum[blockIdx.x] = woff + s;
}

__global__ void scan2(int* __restrict__ bsum, int G, int* __restrict__ offN) {
    __shared__ int w0sum;
    int lane = threadIdx.x & 63, wid = threadIdx.x >> 6;
    int v = (threadIdx.x < G) ? bsum[threadIdx.x] : 0;
    int s = v;
#pragma unroll
    for (int d = 1; d < 64; d <<= 1) {
        int t = __shfl_up(s, d, 64);
        if (lane >= d) s += t;
    }
    if (wid == 0 && lane == 63) w0sum = s;
    __syncthreads();
    int base = wid ? w0sum : 0;
    if (threadIdx.x < G) bsum[threadIdx.x] = base + s - v;  // exclusive
    if (threadIdx.x == G - 1) offN[0] = base + s;           // grand total
}

__global__ void scan3(int* __restrict__ off, int N, const int* __restrict__ bsum) {
    int i = blockIdx.x * 1024 + threadIdx.x;
    if (i < N) off[i] += bsum[blockIdx.x];
}

__global__ void fill_csr(const int* __restrict__ ei, int E, const int* __restrict__ flag,
                         const int* __restrict__ off, int* __restrict__ cur,
                         int* __restrict__ csr) {
    int e = blockIdx.x * blockDim.x + threadIdx.x;
    if (e >= E) return;
    int is64 = flag[0];
    int s = is64 ? ei[2 * e] : ei[e];
    int d = is64 ? ei[2 * (E + e)] : ei[E + e];
    int p = atomicAdd(&cur[d], 1);
    csr[off[d] + p] = s;
}

__global__ void cast_bf16(const float* __restrict__ in, unsigned short* __restrict__ out,
                          int n4) {
    int i = blockIdx.x * blockDim.x + threadIdx.x;
    if (i >= n4) return;
    float4 v = ((const float4*)in)[i];
    ushort4 o;
    o.x = f2bf(v.x); o.y = f2bf(v.y); o.z = f2bf(v.z); o.w = f2bf(v.w);
    ((ushort4*)out)[i] = o;
}

// Wt[f][koff + k] = bf16(W[k][f]), W is 128x128 fp32, Wt row stride 256
__global__ void transpose_cast(const float* __restrict__ W, unsigned short* __restrict__ Wt,
                               int koff) {
    __shared__ float t[32][33];
    int bx = blockIdx.x & 3, by = blockIdx.x >> 2;
    int c = threadIdx.x & 31, r8 = threadIdx.x >> 5;
#pragma unroll
    for (int i = 0; i < 4; i++) {
        int r = r8 + i * 8;
        t[r][c] = W[(by * 32 + r) * 128 + bx * 32 + c];
    }
    __syncthreads();
#pragma unroll
    for (int i = 0; i < 4; i++) {
        int r = r8 + i * 8;
        Wt[(bx * 32 + r) * 256 + koff + by * 32 + c] = f2bf(t[c][r]);
    }
}

// one 64-lane wave per node; lane handles 2 consecutive features
template <typename TI>
__global__ void aggregate(const TI* __restrict__ feat,
                          const int* __restrict__ off, const int* __restrict__ csr,
                          unsigned short* __restrict__ mean, int N,
                          const int* __restrict__ limp) {
    int lim = limp ? min(N, limp[0]) : N;
    int node = blockIdx.x * (blockDim.x >> 6) + (threadIdx.x >> 6);
    if (node >= lim) return;
    int lane = threadIdx.x & 63;
    int s0 = off[node], s1 = off[node + 1];
    float ax = 0.f, ay = 0.f;
    for (int j = s0; j < s1; j++) {
        int s = csr[j];
        float2 v = load2(feat, s * 64 + lane);
        ax += v.x; ay += v.y;
    }
    float inv = (s1 > s0) ? (1.0f / (float)(s1 - s0)) : 0.0f;
    unsigned int p = (unsigned int)f2bf(ax * inv) | ((unsigned int)f2bf(ay * inv) << 16);
    ((unsigned int*)mean)[node * 64 + lane] = p;
}

// out[n][f] = sum_k A1[n][k]*Wt[f][k] (k<128) + A2[n][k]*Wt[f][128+k] + bias[f]
// block: 256 thr = 4 waves in 2x2; block tile 64 M x 128 N; wave tile 32 M x 64 N.
// MFMA 16x16x32 bf16. A-frag: A[m=lane&15][k=quad*8+j]; B mirrored; D: col=lane&15,
// row=quad*4+reg (HW-verified layouts, learn_hip m89/m120).
// K-loop: 8 steps of 32. Global k = ks*32 indexes Wt directly (Wl|Wr packed);
// A side: phase = ks>>2 selects A1/A2, kb = (ks&3)*32 (A rows are 128 wide!).
template <typename TA2, typename TO>
__global__ __launch_bounds__(256) void gemm_mfma(
    const unsigned short* __restrict__ A1, const TA2* __restrict__ A2,
    const unsigned short* __restrict__ Wt, const float* __restrict__ bias,
    TO* __restrict__ out, int Arows, int Nlimit, const int* __restrict__ origp) {
    int lim = Nlimit;
    if (origp) lim = min(lim, origp[0]);
    int n0 = blockIdx.x * 64;
    if (n0 >= lim) return;

    __shared__ unsigned short A_lds[64 * 40];  // stride 40 bf16 = 80 B: 2-way (free)

    int tid = threadIdx.x;
    int lane = tid & 63;
    int wid = tid >> 6;
    int wm = wid >> 1, wn = wid & 1;
    int qd = lane >> 4, l16 = lane & 15;

    f32x4 acc[2][4];
#pragma unroll
    for (int a = 0; a < 2; a++)
#pragma unroll
        for (int b = 0; b < 4; b++) acc[a][b] = (f32x4){0.f, 0.f, 0.f, 0.f};

    int srow = tid >> 2, sq = tid & 3;   // staging: row 0..63, 16B quarter 0..3

    for (int ks = 0; ks < 8; ks++) {
        int phase = ks >> 2;             // 0: A1 (mean), 1: A2 (root)
        int kb = (ks & 3) * 32;          // k offset within the 128-wide A row
        __syncthreads();
        {
            int gn = n0 + srow;
            bf16x8 v = (bf16x8){0, 0, 0, 0, 0, 0, 0, 0};
            if (gn < Arows) {
                if (phase)
                    v = load8_bf(A2 + gn * 128 + kb + sq * 8);
                else
                    v = load8_bf(A1 + gn * 128 + kb + sq * 8);
            }
            *((bf16x8*)(A_lds + srow * 40 + sq * 8)) = v;
        }
        __syncthreads();

        bf16x8 afrag[2];
#pragma unroll
        for (int tm = 0; tm < 2; tm++)
            afrag[tm] = *((const bf16x8*)(A_lds + (wm * 32 + tm * 16 + l16) * 40 + qd * 8));
#pragma unroll
        for (int tn = 0; tn < 4; tn++) {
            int f = wn * 64 + tn * 16 + l16;
            bf16x8 bfrag = *((const bf16x8*)(Wt + f * 256 + ks * 32 + qd * 8));
            acc[0][tn] = __builtin_amdgcn_mfma_f32_16x16x32_bf16(afrag[0], bfrag, acc[0][tn], 0, 0, 0);
            acc[1][tn] = __builtin_amdgcn_mfma_f32_16x16x32_bf16(afrag[1], bfrag, acc[1][tn], 0, 0, 0);
        }
    }

#pragma unroll
    for (int tn = 0; tn < 4; tn++) {
        int f = wn * 64 + tn * 16 + l16;
        float bv = bias[f];
#pragma unroll
        for (int tm = 0; tm < 2; tm++) {
#pragma unroll
            for (int r = 0; r < 4; r++) {
                int n = n0 + wm * 32 + tm * 16 + qd * 4 + r;
                if (n < lim) {
                    float val = acc[tm][tn][r] + bv;
                    if constexpr (__is_same(TO, float))
                        out[n * 128 + f] = val;
                    else
                        out[n * 128 + f] = f2bf(val);
                }
            }
        }
    }
}

extern "C" void kernel_launch(void* const* d_in, const int* in_sizes, int n_in,
                              void* d_out, int out_size, void* d_ws, size_t ws_size,
                              hipStream_t stream) {
    const float* x   = (const float*)d_in[0];
    const int*   ei  = (const int*)d_in[1];
    const int*   org = (const int*)d_in[2];
    const float* Wl1 = (const float*)d_in[3];
    const float* bl1 = (const float*)d_in[4];
    const float* Wr1 = (const float*)d_in[5];
    const float* Wl2 = (const float*)d_in[6];
    const float* bl2 = (const float*)d_in[7];
    const float* Wr2 = (const float*)d_in[8];
    float* out = (float*)d_out;

    const int N = in_sizes[0] / DD;
    const int E = in_sizes[1] / 2;

    size_t szFeat = (size_t)N * DD * 2;          // bf16 feature matrix
    size_t szBase = 2 * szFeat                    // mean + h
                  + 2 * 65536                     // Wt1 + Wt2
                  + (size_t)N * 4 * 2             // cnt + cur
                  + (size_t)(N + 1) * 4           // off
                  + 64 + 1024                     // flag + bsum
                  + (size_t)E * 4;                // csr
    bool big = ws_size >= szBase + szFeat + 4096; // room for bf16 x too?

    char* ws = (char*)d_ws;
    unsigned short* mean = (unsigned short*)ws;  ws += szFeat;
    unsigned short* h    = (unsigned short*)ws;  ws += szFeat;
    unsigned short* xb   = nullptr;
    if (big) { xb = (unsigned short*)ws; ws += szFeat; }
    unsigned short* Wt1 = (unsigned short*)ws;  ws += 65536;
    unsigned short* Wt2 = (unsigned short*)ws;  ws += 65536;
    int* cnt  = (int*)ws;  ws += (size_t)N * 4;
    int* cur  = (int*)ws;  ws += (size_t)N * 4;
    int* off  = (int*)ws;  ws += (size_t)(N + 1) * 4;
    int* flag = (int*)ws;  ws += 64;
    int* bsum = (int*)ws;  ws += 1024;
    int* csr  = (int*)ws;

    int scanG = (N + 1023) / 1024;  // 98 for N=100000 (scan2 requires <=128)

    // --- CSR build ---
    zero_ints<<<(2 * N + 255) / 256, 256, 0, stream>>>(cnt, 2 * N);
    detect64<<<1, 64, 0, stream>>>(ei, flag);
    count_deg<<<(E + 255) / 256, 256, 0, stream>>>(ei, E, flag, cnt);
    scan1<<<scanG, 1024, 0, stream>>>(cnt, N, off, bsum);
    scan2<<<1, 128, 0, stream>>>(bsum, scanG, off + N);
    scan3<<<scanG, 1024, 0, stream>>>(off, N, bsum);
    fill_csr<<<(E + 255) / 256, 256, 0, stream>>>(ei, E, flag, off, cur, csr);

    // --- weight prep (Wt[f][k]: k<128 = Wl, k>=128 = Wr) ---
    transpose_cast<<<16, 256, 0, stream>>>(Wl1, Wt1, 0);
    transpose_cast<<<16, 256, 0, stream>>>(Wr1, Wt1, 128);
    transpose_cast<<<16, 256, 0, stream>>>(Wl2, Wt2, 0);
    transpose_cast<<<16, 256, 0, stream>>>(Wr2, Wt2, 128);

    int aggGrid  = (N + 3) / 4;
    int gemmGrid = (N + 63) / 64;

    if (big) {
        cast_bf16<<<(N * DD / 4 + 255) / 256, 256, 0, stream>>>(x, xb, N * DD / 4);
        aggregate<unsigned short><<<aggGrid, 256, 0, stream>>>(xb, off, csr, mean, N, nullptr);
        gemm_mfma<unsigned short, unsigned short><<<gemmGrid, 256, 0, stream>>>(
            mean, xb, Wt1, bl1, h, N, N, nullptr);
    } else {
        aggregate<float><<<aggGrid, 256, 0, stream>>>(x, off, csr, mean, N, nullptr);
        gemm_mfma<float, unsigned short><<<gemmGrid, 256, 0, stream>>>(
            mean, x, Wt1, bl1, h, N, N, nullptr);
    }
    aggregate<unsigned short><<<aggGrid, 256, 0, stream>>>(h, off, csr, mean, N, org);
    gemm_mfma<unsigned short, float><<<gemmGrid, 256, 0, stream>>>(
        mean, h, Wt2, bl2, out, N, N, org);
}

// Round 5
// 498.075 us; speedup vs baseline: 1.6941x; 1.3603x over previous
//
#include <hip/hip_runtime.h>

#define NN 100000
#define DD 128

typedef __attribute__((ext_vector_type(8))) short bf16x8;
typedef __attribute__((ext_vector_type(4))) float f32x4;

__device__ __forceinline__ float bf2f(unsigned short u) {
    union { unsigned int i; float f; } v;
    v.i = ((unsigned int)u) << 16;
    return v.f;
}

__device__ __forceinline__ unsigned short f2bf(float f) {
    union { float f; unsigned int i; } v;
    v.f = f;
    unsigned int x = v.i;
    return (unsigned short)((x + 0x7FFFu + ((x >> 16) & 1u)) >> 16);
}

__device__ __forceinline__ float2 load2(const float* p, int i2) {
    return ((const float2*)p)[i2];
}

// 8 bf16 elements from bf16 or fp32 storage (for GEMM A staging)
__device__ __forceinline__ bf16x8 load8_bf(const unsigned short* p) {
    return *((const bf16x8*)p);
}
__device__ __forceinline__ bf16x8 load8_bf(const float* p) {
    float4 a = ((const float4*)p)[0];
    float4 b = ((const float4*)p)[1];
    bf16x8 r;
    r[0] = (short)f2bf(a.x); r[1] = (short)f2bf(a.y);
    r[2] = (short)f2bf(a.z); r[3] = (short)f2bf(a.w);
    r[4] = (short)f2bf(b.x); r[5] = (short)f2bf(b.y);
    r[6] = (short)f2bf(b.z); r[7] = (short)f2bf(b.w);
    return r;
}

// int64 little-endian edges with values < 2^31 => odd int32 words all zero.
// Per-block detection: wave 0 checks 64 samples, shares via LDS.
__device__ __forceinline__ int block_is64(const int* __restrict__ ei) {
    __shared__ int is64_s;
    if (threadIdx.x < 64) {
        int ok = (ei[2 * threadIdx.x + 1] == 0);
        int all = __all(ok);
        if (threadIdx.x == 0) is64_s = all;
    }
    __syncthreads();
    return is64_s;
}

__global__ void count_deg(const int* __restrict__ ei, int E, int* __restrict__ cnt) {
    int is64 = block_is64(ei);
    int e = blockIdx.x * blockDim.x + threadIdx.x;
    if (e >= E) return;
    int d = is64 ? ei[2 * (E + e)] : ei[E + e];
    atomicAdd(&cnt[d], 1);
}

// ---- multi-block scan (3 passes) ----
__global__ void scan1(const int* __restrict__ cnt, int N, int* __restrict__ off,
                      int* __restrict__ bsum) {
    __shared__ int wsum[16];
    int i = blockIdx.x * 1024 + threadIdx.x;
    int lane = threadIdx.x & 63, wid = threadIdx.x >> 6;
    int v = (i < N) ? cnt[i] : 0;
    int s = v;
#pragma unroll
    for (int d = 1; d < 64; d <<= 1) {
        int t = __shfl_up(s, d, 64);
        if (lane >= d) s += t;
    }
    if (lane == 63) wsum[wid] = s;
    __syncthreads();
    int woff = 0;
#pragma unroll
    for (int w = 0; w < 16; w++) woff += (w < wid) ? wsum[w] : 0;
    if (i < N) off[i] = woff + s - v;   // block-local exclusive
    if (threadIdx.x == 1023) bsum[blockIdx.x] = woff + s;
}

__global__ void scan2(int* __restrict__ bsum, int G, int* __restrict__ offN) {
    __shared__ int w0sum;
    int lane = threadIdx.x & 63, wid = threadIdx.x >> 6;
    int v = (threadIdx.x < G) ? bsum[threadIdx.x] : 0;
    int s = v;
#pragma unroll
    for (int d = 1; d < 64; d <<= 1) {
        int t = __shfl_up(s, d, 64);
        if (lane >= d) s += t;
    }
    if (wid == 0 && lane == 63) w0sum = s;
    __syncthreads();
    int base = wid ? w0sum : 0;
    if (threadIdx.x < G) bsum[threadIdx.x] = base + s - v;  // exclusive
    if (threadIdx.x == G - 1) offN[0] = base + s;           // grand total
}

__global__ void scan3(int* __restrict__ off, int N, const int* __restrict__ bsum) {
    int i = blockIdx.x * 1024 + threadIdx.x;
    if (i < N) off[i] += bsum[blockIdx.x];
}

__global__ void fill_csr(const int* __restrict__ ei, int E,
                         const int* __restrict__ off, int* __restrict__ cur,
                         int* __restrict__ csr) {
    int is64 = block_is64(ei);
    int e = blockIdx.x * blockDim.x + threadIdx.x;
    if (e >= E) return;
    int s = is64 ? ei[2 * e] : ei[e];
    int d = is64 ? ei[2 * (E + e)] : ei[E + e];
    int p = atomicAdd(&cur[d], 1);
    csr[off[d] + p] = s;
}

__global__ void cast_bf16(const float* __restrict__ in, unsigned short* __restrict__ out,
                          int n4) {
    int i = blockIdx.x * blockDim.x + threadIdx.x;
    if (i >= n4) return;
    float4 v = ((const float4*)in)[i];
    ushort4 o;
    o.x = f2bf(v.x); o.y = f2bf(v.y); o.z = f2bf(v.z); o.w = f2bf(v.w);
    ((ushort4*)out)[i] = o;
}

// All 4 weight transposes in one launch. Wt[f][koff+k] = bf16(W[k][f]).
// grid 64: blockIdx>>4 selects matrix, &15 selects 32x32 sub-tile.
__global__ void prep_weights(const float* __restrict__ Wl1, const float* __restrict__ Wr1,
                             const float* __restrict__ Wl2, const float* __restrict__ Wr2,
                             unsigned short* __restrict__ Wt1, unsigned short* __restrict__ Wt2) {
    __shared__ float t[32][33];
    int which = blockIdx.x >> 4;
    const float* W = (which == 0) ? Wl1 : (which == 1) ? Wr1 : (which == 2) ? Wl2 : Wr2;
    unsigned short* Wt = (which < 2) ? Wt1 : Wt2;
    int koff = (which & 1) * 128;
    int b = blockIdx.x & 15;
    int bx = b & 3, by = b >> 2;
    int c = threadIdx.x & 31, r8 = threadIdx.x >> 5;
#pragma unroll
    for (int i = 0; i < 4; i++) {
        int r = r8 + i * 8;
        t[r][c] = W[(by * 32 + r) * 128 + bx * 32 + c];
    }
    __syncthreads();
#pragma unroll
    for (int i = 0; i < 4; i++) {
        int r = r8 + i * 8;
        Wt[(bx * 32 + r) * 256 + koff + by * 32 + c] = f2bf(t[c][r]);
    }
}

// Fast aggregate (bf16 features): one wave per node.
// lane = (e = lane>>4: edge slot, q = lane&15: feature octet).
// Per iteration: 4 edges x 16 B/lane = 1 KB/wave in flight; unrolled x2 (8 edges).
// Cross-slot reduce: shfl_xor 16/32 at node end.
__global__ __launch_bounds__(256) void aggregate_bf(
    const unsigned short* __restrict__ feat,
    const int* __restrict__ off, const int* __restrict__ csr,
    unsigned short* __restrict__ mean, int N, const int* __restrict__ limp) {
    int lim = limp ? min(N, limp[0]) : N;
    int node = blockIdx.x * (blockDim.x >> 6) + (threadIdx.x >> 6);
    if (node >= lim) return;
    int lane = threadIdx.x & 63;
    int e = lane >> 4, q = lane & 15;
    int s0 = off[node], s1 = off[node + 1];

    float acc[8];
#pragma unroll
    for (int t = 0; t < 8; t++) acc[t] = 0.f;

    int j = s0 + e;
    // unrolled x2: issue both csr loads, then both feature loads, then accumulate
    while (j + 4 < s1) {
        int sa = csr[j];
        int sb = csr[j + 4];
        bf16x8 va = *((const bf16x8*)(feat + (size_t)sa * 128 + q * 8));
        bf16x8 vb = *((const bf16x8*)(feat + (size_t)sb * 128 + q * 8));
#pragma unroll
        for (int t = 0; t < 8; t++) acc[t] += bf2f((unsigned short)va[t]);
#pragma unroll
        for (int t = 0; t < 8; t++) acc[t] += bf2f((unsigned short)vb[t]);
        j += 8;
    }
    if (j < s1) {
        int sa = csr[j];
        bf16x8 va = *((const bf16x8*)(feat + (size_t)sa * 128 + q * 8));
#pragma unroll
        for (int t = 0; t < 8; t++) acc[t] += bf2f((unsigned short)va[t]);
    }

#pragma unroll
    for (int t = 0; t < 8; t++) {
        acc[t] += __shfl_xor(acc[t], 16, 64);
        acc[t] += __shfl_xor(acc[t], 32, 64);
    }

    int deg = s1 - s0;
    float inv = (deg > 0) ? (1.0f / (float)deg) : 0.0f;
    if (e == 0) {
        bf16x8 o;
#pragma unroll
        for (int t = 0; t < 8; t++) o[t] = (short)f2bf(acc[t] * inv);
        *((bf16x8*)(mean + (size_t)node * 128 + q * 8)) = o;
    }
}

// Fallback scalar aggregate for fp32 features (non-big path only)
__global__ void aggregate_f32(const float* __restrict__ feat,
                              const int* __restrict__ off, const int* __restrict__ csr,
                              unsigned short* __restrict__ mean, int N) {
    int node = blockIdx.x * (blockDim.x >> 6) + (threadIdx.x >> 6);
    if (node >= N) return;
    int lane = threadIdx.x & 63;
    int s0 = off[node], s1 = off[node + 1];
    float ax = 0.f, ay = 0.f;
    for (int j = s0; j < s1; j++) {
        int s = csr[j];
        float2 v = load2(feat, s * 64 + lane);
        ax += v.x; ay += v.y;
    }
    float inv = (s1 > s0) ? (1.0f / (float)(s1 - s0)) : 0.0f;
    unsigned int p = (unsigned int)f2bf(ax * inv) | ((unsigned int)f2bf(ay * inv) << 16);
    ((unsigned int*)mean)[node * 64 + lane] = p;
}

// out[n][f] = sum_k A1[n][k]*Wt[f][k] (k<128) + A2[n][k]*Wt[f][128+k] + bias[f]
// block: 256 thr = 4 waves in 2x2; block tile 64 M x 128 N; wave tile 32 M x 64 N.
// MFMA 16x16x32 bf16. A-frag: A[m=lane&15][k=quad*8+j]; B mirrored; D: col=lane&15,
// row=quad*4+reg (HW-verified layouts, learn_hip m89/m120).
template <typename TA2, typename TO>
__global__ __launch_bounds__(256) void gemm_mfma(
    const unsigned short* __restrict__ A1, const TA2* __restrict__ A2,
    const unsigned short* __restrict__ Wt, const float* __restrict__ bias,
    TO* __restrict__ out, int Arows, int Nlimit, const int* __restrict__ origp) {
    int lim = Nlimit;
    if (origp) lim = min(lim, origp[0]);
    int n0 = blockIdx.x * 64;
    if (n0 >= lim) return;

    __shared__ unsigned short A_lds[64 * 40];  // stride 40 bf16 = 80 B: 2-way (free)

    int tid = threadIdx.x;
    int lane = tid & 63;
    int wid = tid >> 6;
    int wm = wid >> 1, wn = wid & 1;
    int qd = lane >> 4, l16 = lane & 15;

    f32x4 acc[2][4];
#pragma unroll
    for (int a = 0; a < 2; a++)
#pragma unroll
        for (int b = 0; b < 4; b++) acc[a][b] = (f32x4){0.f, 0.f, 0.f, 0.f};

    int srow = tid >> 2, sq = tid & 3;   // staging: row 0..63, 16B quarter 0..3

    for (int ks = 0; ks < 8; ks++) {
        int phase = ks >> 2;             // 0: A1 (mean), 1: A2 (root)
        int kb = (ks & 3) * 32;          // k offset within the 128-wide A row
        __syncthreads();
        {
            int gn = n0 + srow;
            bf16x8 v = (bf16x8){0, 0, 0, 0, 0, 0, 0, 0};
            if (gn < Arows) {
                if (phase)
                    v = load8_bf(A2 + gn * 128 + kb + sq * 8);
                else
                    v = load8_bf(A1 + gn * 128 + kb + sq * 8);
            }
            *((bf16x8*)(A_lds + srow * 40 + sq * 8)) = v;
        }
        __syncthreads();

        bf16x8 afrag[2];
#pragma unroll
        for (int tm = 0; tm < 2; tm++)
            afrag[tm] = *((const bf16x8*)(A_lds + (wm * 32 + tm * 16 + l16) * 40 + qd * 8));
#pragma unroll
        for (int tn = 0; tn < 4; tn++) {
            int f = wn * 64 + tn * 16 + l16;
            bf16x8 bfrag = *((const bf16x8*)(Wt + f * 256 + ks * 32 + qd * 8));
            acc[0][tn] = __builtin_amdgcn_mfma_f32_16x16x32_bf16(afrag[0], bfrag, acc[0][tn], 0, 0, 0);
            acc[1][tn] = __builtin_amdgcn_mfma_f32_16x16x32_bf16(afrag[1], bfrag, acc[1][tn], 0, 0, 0);
        }
    }

#pragma unroll
    for (int tn = 0; tn < 4; tn++) {
        int f = wn * 64 + tn * 16 + l16;
        float bv = bias[f];
#pragma unroll
        for (int tm = 0; tm < 2; tm++) {
#pragma unroll
            for (int r = 0; r < 4; r++) {
                int n = n0 + wm * 32 + tm * 16 + qd * 4 + r;
                if (n < lim) {
                    float val = acc[tm][tn][r] + bv;
                    if constexpr (__is_same(TO, float))
                        out[n * 128 + f] = val;
                    else
                        out[n * 128 + f] = f2bf(val);
                }
            }
        }
    }
}

extern "C" void kernel_launch(void* const* d_in, const int* in_sizes, int n_in,
                              void* d_out, int out_size, void* d_ws, size_t ws_size,
                              hipStream_t stream) {
    const float* x   = (const float*)d_in[0];
    const int*   ei  = (const int*)d_in[1];
    const int*   org = (const int*)d_in[2];
    const float* Wl1 = (const float*)d_in[3];
    const float* bl1 = (const float*)d_in[4];
    const float* Wr1 = (const float*)d_in[5];
    const float* Wl2 = (const float*)d_in[6];
    const float* bl2 = (const float*)d_in[7];
    const float* Wr2 = (const float*)d_in[8];
    float* out = (float*)d_out;

    const int N = in_sizes[0] / DD;
    const int E = in_sizes[1] / 2;

    size_t szFeat = (size_t)N * DD * 2;          // bf16 feature matrix
    size_t szBase = 2 * szFeat                    // mean + h
                  + 2 * 65536                     // Wt1 + Wt2
                  + (size_t)N * 4 * 2             // cnt + cur
                  + (size_t)(N + 1) * 4           // off
                  + 1024                          // bsum
                  + (size_t)E * 4;                // csr
    bool big = ws_size >= szBase + szFeat + 4096; // room for bf16 x too?

    char* ws = (char*)d_ws;
    unsigned short* mean = (unsigned short*)ws;  ws += szFeat;
    unsigned short* h    = (unsigned short*)ws;  ws += szFeat;
    unsigned short* xb   = nullptr;
    if (big) { xb = (unsigned short*)ws; ws += szFeat; }
    unsigned short* Wt1 = (unsigned short*)ws;  ws += 65536;
    unsigned short* Wt2 = (unsigned short*)ws;  ws += 65536;
    int* cnt  = (int*)ws;  ws += (size_t)N * 4;
    int* cur  = (int*)ws;  ws += (size_t)N * 4;   // adjacent to cnt: one memset
    int* off  = (int*)ws;  ws += (size_t)(N + 1) * 4;
    int* bsum = (int*)ws;  ws += 1024;
    int* csr  = (int*)ws;

    int scanG = (N + 1023) / 1024;  // 98 for N=100000 (scan2 requires <=128)

    // --- CSR build ---
    hipMemsetAsync(cnt, 0, (size_t)2 * N * 4, stream);      // cnt + cur
    count_deg<<<(E + 255) / 256, 256, 0, stream>>>(ei, E, cnt);
    scan1<<<scanG, 1024, 0, stream>>>(cnt, N, off, bsum);
    scan2<<<1, 128, 0, stream>>>(bsum, scanG, off + N);
    scan3<<<scanG, 1024, 0, stream>>>(off, N, bsum);
    fill_csr<<<(E + 255) / 256, 256, 0, stream>>>(ei, E, off, cur, csr);

    // --- weight prep (Wt[f][k]: k<128 = Wl, k>=128 = Wr) ---
    prep_weights<<<64, 256, 0, stream>>>(Wl1, Wr1, Wl2, Wr2, Wt1, Wt2);

    int aggGrid  = (N + 3) / 4;
    int gemmGrid = (N + 63) / 64;

    if (big) {
        cast_bf16<<<(N * DD / 4 + 255) / 256, 256, 0, stream>>>(x, xb, N * DD / 4);
        aggregate_bf<<<aggGrid, 256, 0, stream>>>(xb, off, csr, mean, N, nullptr);
        gemm_mfma<unsigned short, unsigned short><<<gemmGrid, 256, 0, stream>>>(
            mean, xb, Wt1, bl1, h, N, N, nullptr);
    } else {
        aggregate_f32<<<aggGrid, 256, 0, stream>>>(x, off, csr, mean, N);
        gemm_mfma<float, unsigned short><<<gemmGrid, 256, 0, stream>>>(
            mean, x, Wt1, bl1, h, N, N, nullptr);
    }
    aggregate_bf<<<aggGrid, 256, 0, stream>>>(h, off, csr, mean, N, org);
    gemm_mfma<unsigned short, float><<<gemmGrid, 256, 0, stream>>>(
        mean, h, Wt2, bl2, out, N, N, org);
}

// Round 6
// 468.624 us; speedup vs baseline: 1.8005x; 1.0628x over previous
//
#include <hip/hip_runtime.h>

#define NN 100000
#define DD 128

typedef __attribute__((ext_vector_type(8))) short bf16x8;
typedef __attribute__((ext_vector_type(4))) float f32x4;

__device__ __forceinline__ float bf2f(unsigned short u) {
    union { unsigned int i; float f; } v;
    v.i = ((unsigned int)u) << 16;
    return v.f;
}

__device__ __forceinline__ unsigned short f2bf(float f) {
    union { float f; unsigned int i; } v;
    v.f = f;
    unsigned int x = v.i;
    return (unsigned short)((x + 0x7FFFu + ((x >> 16) & 1u)) >> 16);
}

__device__ __forceinline__ float2 load2(const float* p, int i2) {
    return ((const float2*)p)[i2];
}

// 8 bf16 elements from bf16 or fp32 storage (for GEMM A staging)
__device__ __forceinline__ bf16x8 load8_bf(const unsigned short* p) {
    return *((const bf16x8*)p);
}
__device__ __forceinline__ bf16x8 load8_bf(const float* p) {
    float4 a = ((const float4*)p)[0];
    float4 b = ((const float4*)p)[1];
    bf16x8 r;
    r[0] = (short)f2bf(a.x); r[1] = (short)f2bf(a.y);
    r[2] = (short)f2bf(a.z); r[3] = (short)f2bf(a.w);
    r[4] = (short)f2bf(b.x); r[5] = (short)f2bf(b.y);
    r[6] = (short)f2bf(b.z); r[7] = (short)f2bf(b.w);
    return r;
}

// int64 little-endian edges with values < 2^31 => odd int32 words all zero.
// Per-block detection: wave 0 checks 64 samples, shares via LDS.
__device__ __forceinline__ int block_is64(const int* __restrict__ ei) {
    __shared__ int is64_s;
    if (threadIdx.x < 64) {
        int ok = (ei[2 * threadIdx.x + 1] == 0);
        int all = __all(ok);
        if (threadIdx.x == 0) is64_s = all;
    }
    __syncthreads();
    return is64_s;
}

__global__ void count_deg(const int* __restrict__ ei, int E, int* __restrict__ cnt) {
    int is64 = block_is64(ei);
    int e = blockIdx.x * blockDim.x + threadIdx.x;
    if (e >= E) return;
    int d = is64 ? ei[2 * (E + e)] : ei[E + e];
    atomicAdd(&cnt[d], 1);
}

// ---- multi-block scan (3 passes) ----
__global__ void scan1(const int* __restrict__ cnt, int N, int* __restrict__ off,
                      int* __restrict__ bsum) {
    __shared__ int wsum[16];
    int i = blockIdx.x * 1024 + threadIdx.x;
    int lane = threadIdx.x & 63, wid = threadIdx.x >> 6;
    int v = (i < N) ? cnt[i] : 0;
    int s = v;
#pragma unroll
    for (int d = 1; d < 64; d <<= 1) {
        int t = __shfl_up(s, d, 64);
        if (lane >= d) s += t;
    }
    if (lane == 63) wsum[wid] = s;
    __syncthreads();
    int woff = 0;
#pragma unroll
    for (int w = 0; w < 16; w++) woff += (w < wid) ? wsum[w] : 0;
    if (i < N) off[i] = woff + s - v;   // block-local exclusive
    if (threadIdx.x == 1023) bsum[blockIdx.x] = woff + s;
}

__global__ void scan2(int* __restrict__ bsum, int G, int* __restrict__ offN) {
    __shared__ int w0sum;
    int lane = threadIdx.x & 63, wid = threadIdx.x >> 6;
    int v = (threadIdx.x < G) ? bsum[threadIdx.x] : 0;
    int s = v;
#pragma unroll
    for (int d = 1; d < 64; d <<= 1) {
        int t = __shfl_up(s, d, 64);
        if (lane >= d) s += t;
    }
    if (wid == 0 && lane == 63) w0sum = s;
    __syncthreads();
    int base = wid ? w0sum : 0;
    if (threadIdx.x < G) bsum[threadIdx.x] = base + s - v;  // exclusive
    if (threadIdx.x == G - 1) offN[0] = base + s;           // grand total
}

__global__ void scan3(int* __restrict__ off, int N, const int* __restrict__ bsum) {
    int i = blockIdx.x * 1024 + threadIdx.x;
    if (i < N) off[i] += bsum[blockIdx.x];
}

// Sweep-partitioned CSR fill. Round-5 profile: single-pass version wrote 107 MB
// for 6.4 MB of payload (16x line amplification: random 4 B scatters over a
// 6.4 MB region > 4 MB per-XCD L2, partially-dirty lines evicted early).
// Fix: blockIdx.y = sweep handles only dst in [sweep*range, (sweep+1)*range)
// -> per-sweep csr window ~1.6 MB + cur window ~100 KB stay L2-resident,
// lines fill fully before write-back. Edge re-reads come from L3.
__global__ void fill_csr(const int* __restrict__ ei, int E,
                         const int* __restrict__ off, int* __restrict__ cur,
                         int* __restrict__ csr, int range) {
    int is64 = block_is64(ei);
    int e = blockIdx.x * blockDim.x + threadIdx.x;
    if (e >= E) return;
    int d = is64 ? ei[2 * (E + e)] : ei[E + e];
    int lo = blockIdx.y * range;
    if (d < lo || d >= lo + range) return;
    int s = is64 ? ei[2 * e] : ei[e];
    int p = atomicAdd(&cur[d], 1);
    csr[off[d] + p] = s;
}

__global__ void cast_bf16(const float* __restrict__ in, unsigned short* __restrict__ out,
                          int n4) {
    int i = blockIdx.x * blockDim.x + threadIdx.x;
    if (i >= n4) return;
    float4 v = ((const float4*)in)[i];
    ushort4 o;
    o.x = f2bf(v.x); o.y = f2bf(v.y); o.z = f2bf(v.z); o.w = f2bf(v.w);
    ((ushort4*)out)[i] = o;
}

// All 4 weight transposes in one launch. Wt[f][koff+k] = bf16(W[k][f]).
// grid 64: blockIdx>>4 selects matrix, &15 selects 32x32 sub-tile.
__global__ void prep_weights(const float* __restrict__ Wl1, const float* __restrict__ Wr1,
                             const float* __restrict__ Wl2, const float* __restrict__ Wr2,
                             unsigned short* __restrict__ Wt1, unsigned short* __restrict__ Wt2) {
    __shared__ float t[32][33];
    int which = blockIdx.x >> 4;
    const float* W = (which == 0) ? Wl1 : (which == 1) ? Wr1 : (which == 2) ? Wl2 : Wr2;
    unsigned short* Wt = (which < 2) ? Wt1 : Wt2;
    int koff = (which & 1) * 128;
    int b = blockIdx.x & 15;
    int bx = b & 3, by = b >> 2;
    int c = threadIdx.x & 31, r8 = threadIdx.x >> 5;
#pragma unroll
    for (int i = 0; i < 4; i++) {
        int r = r8 + i * 8;
        t[r][c] = W[(by * 32 + r) * 128 + bx * 32 + c];
    }
    __syncthreads();
#pragma unroll
    for (int i = 0; i < 4; i++) {
        int r = r8 + i * 8;
        Wt[(bx * 32 + r) * 256 + koff + by * 32 + c] = f2bf(t[c][r]);
    }
}

// Fast aggregate (bf16 features): one wave per node.
// lane = (e = lane>>4: edge slot, q = lane&15: feature octet).
// Per iteration: 4 edges x 16 B/lane = 1 KB/wave in flight; unrolled x2 (8 edges).
// Cross-slot reduce: shfl_xor 16/32 at node end.
__global__ __launch_bounds__(256) void aggregate_bf(
    const unsigned short* __restrict__ feat,
    const int* __restrict__ off, const int* __restrict__ csr,
    unsigned short* __restrict__ mean, int N, const int* __restrict__ limp) {
    int lim = limp ? min(N, limp[0]) : N;
    int node = blockIdx.x * (blockDim.x >> 6) + (threadIdx.x >> 6);
    if (node >= lim) return;
    int lane = threadIdx.x & 63;
    int e = lane >> 4, q = lane & 15;
    int s0 = off[node], s1 = off[node + 1];

    float acc[8];
#pragma unroll
    for (int t = 0; t < 8; t++) acc[t] = 0.f;

    int j = s0 + e;
    // unrolled x2: issue both csr loads, then both feature loads, then accumulate
    while (j + 4 < s1) {
        int sa = csr[j];
        int sb = csr[j + 4];
        bf16x8 va = *((const bf16x8*)(feat + (size_t)sa * 128 + q * 8));
        bf16x8 vb = *((const bf16x8*)(feat + (size_t)sb * 128 + q * 8));
#pragma unroll
        for (int t = 0; t < 8; t++) acc[t] += bf2f((unsigned short)va[t]);
#pragma unroll
        for (int t = 0; t < 8; t++) acc[t] += bf2f((unsigned short)vb[t]);
        j += 8;
    }
    if (j < s1) {
        int sa = csr[j];
        bf16x8 va = *((const bf16x8*)(feat + (size_t)sa * 128 + q * 8));
#pragma unroll
        for (int t = 0; t < 8; t++) acc[t] += bf2f((unsigned short)va[t]);
    }

#pragma unroll
    for (int t = 0; t < 8; t++) {
        acc[t] += __shfl_xor(acc[t], 16, 64);
        acc[t] += __shfl_xor(acc[t], 32, 64);
    }

    int deg = s1 - s0;
    float inv = (deg > 0) ? (1.0f / (float)deg) : 0.0f;
    if (e == 0) {
        bf16x8 o;
#pragma unroll
        for (int t = 0; t < 8; t++) o[t] = (short)f2bf(acc[t] * inv);
        *((bf16x8*)(mean + (size_t)node * 128 + q * 8)) = o;
    }
}

// Fallback scalar aggregate for fp32 features (non-big path only)
__global__ void aggregate_f32(const float* __restrict__ feat,
                              const int* __restrict__ off, const int* __restrict__ csr,
                              unsigned short* __restrict__ mean, int N) {
    int node = blockIdx.x * (blockDim.x >> 6) + (threadIdx.x >> 6);
    if (node >= N) return;
    int lane = threadIdx.x & 63;
    int s0 = off[node], s1 = off[node + 1];
    float ax = 0.f, ay = 0.f;
    for (int j = s0; j < s1; j++) {
        int s = csr[j];
        float2 v = load2(feat, s * 64 + lane);
        ax += v.x; ay += v.y;
    }
    float inv = (s1 > s0) ? (1.0f / (float)(s1 - s0)) : 0.0f;
    unsigned int p = (unsigned int)f2bf(ax * inv) | ((unsigned int)f2bf(ay * inv) << 16);
    ((unsigned int*)mean)[node * 64 + lane] = p;
}

// out[n][f] = sum_k A1[n][k]*Wt[f][k] (k<128) + A2[n][k]*Wt[f][128+k] + bias[f]
// block: 256 thr = 4 waves in 2x2; block tile 64 M x 128 N; wave tile 32 M x 64 N.
// MFMA 16x16x32 bf16. A-frag: A[m=lane&15][k=quad*8+j]; B mirrored; D: col=lane&15,
// row=quad*4+reg (HW-verified layouts, learn_hip m89/m120).
template <typename TA2, typename TO>
__global__ __launch_bounds__(256) void gemm_mfma(
    const unsigned short* __restrict__ A1, const TA2* __restrict__ A2,
    const unsigned short* __restrict__ Wt, const float* __restrict__ bias,
    TO* __restrict__ out, int Arows, int Nlimit, const int* __restrict__ origp) {
    int lim = Nlimit;
    if (origp) lim = min(lim, origp[0]);
    int n0 = blockIdx.x * 64;
    if (n0 >= lim) return;

    __shared__ unsigned short A_lds[64 * 40];  // stride 40 bf16 = 80 B: 2-way (free)

    int tid = threadIdx.x;
    int lane = tid & 63;
    int wid = tid >> 6;
    int wm = wid >> 1, wn = wid & 1;
    int qd = lane >> 4, l16 = lane & 15;

    f32x4 acc[2][4];
#pragma unroll
    for (int a = 0; a < 2; a++)
#pragma unroll
        for (int b = 0; b < 4; b++) acc[a][b] = (f32x4){0.f, 0.f, 0.f, 0.f};

    int srow = tid >> 2, sq = tid & 3;   // staging: row 0..63, 16B quarter 0..3

    for (int ks = 0; ks < 8; ks++) {
        int phase = ks >> 2;             // 0: A1 (mean), 1: A2 (root)
        int kb = (ks & 3) * 32;          // k offset within the 128-wide A row
        __syncthreads();
        {
            int gn = n0 + srow;
            bf16x8 v = (bf16x8){0, 0, 0, 0, 0, 0, 0, 0};
            if (gn < Arows) {
                if (phase)
                    v = load8_bf(A2 + gn * 128 + kb + sq * 8);
                else
                    v = load8_bf(A1 + gn * 128 + kb + sq * 8);
            }
            *((bf16x8*)(A_lds + srow * 40 + sq * 8)) = v;
        }
        __syncthreads();

        bf16x8 afrag[2];
#pragma unroll
        for (int tm = 0; tm < 2; tm++)
            afrag[tm] = *((const bf16x8*)(A_lds + (wm * 32 + tm * 16 + l16) * 40 + qd * 8));
#pragma unroll
        for (int tn = 0; tn < 4; tn++) {
            int f = wn * 64 + tn * 16 + l16;
            bf16x8 bfrag = *((const bf16x8*)(Wt + f * 256 + ks * 32 + qd * 8));
            acc[0][tn] = __builtin_amdgcn_mfma_f32_16x16x32_bf16(afrag[0], bfrag, acc[0][tn], 0, 0, 0);
            acc[1][tn] = __builtin_amdgcn_mfma_f32_16x16x32_bf16(afrag[1], bfrag, acc[1][tn], 0, 0, 0);
        }
    }

#pragma unroll
    for (int tn = 0; tn < 4; tn++) {
        int f = wn * 64 + tn * 16 + l16;
        float bv = bias[f];
#pragma unroll
        for (int tm = 0; tm < 2; tm++) {
#pragma unroll
            for (int r = 0; r < 4; r++) {
                int n = n0 + wm * 32 + tm * 16 + qd * 4 + r;
                if (n < lim) {
                    float val = acc[tm][tn][r] + bv;
                    if constexpr (__is_same(TO, float))
                        out[n * 128 + f] = val;
                    else
                        out[n * 128 + f] = f2bf(val);
                }
            }
        }
    }
}

extern "C" void kernel_launch(void* const* d_in, const int* in_sizes, int n_in,
                              void* d_out, int out_size, void* d_ws, size_t ws_size,
                              hipStream_t stream) {
    const float* x   = (const float*)d_in[0];
    const int*   ei  = (const int*)d_in[1];
    const int*   org = (const int*)d_in[2];
    const float* Wl1 = (const float*)d_in[3];
    const float* bl1 = (const float*)d_in[4];
    const float* Wr1 = (const float*)d_in[5];
    const float* Wl2 = (const float*)d_in[6];
    const float* bl2 = (const float*)d_in[7];
    const float* Wr2 = (const float*)d_in[8];
    float* out = (float*)d_out;

    const int N = in_sizes[0] / DD;
    const int E = in_sizes[1] / 2;

    size_t szFeat = (size_t)N * DD * 2;          // bf16 feature matrix
    size_t szBase = 2 * szFeat                    // mean + h
                  + 2 * 65536                     // Wt1 + Wt2
                  + (size_t)N * 4 * 2             // cnt + cur
                  + (size_t)(N + 1) * 4           // off
                  + 1024                          // bsum
                  + (size_t)E * 4;                // csr
    bool big = ws_size >= szBase + szFeat + 4096; // room for bf16 x too?

    char* ws = (char*)d_ws;
    unsigned short* mean = (unsigned short*)ws;  ws += szFeat;
    unsigned short* h    = (unsigned short*)ws;  ws += szFeat;
    unsigned short* xb   = nullptr;
    if (big) { xb = (unsigned short*)ws; ws += szFeat; }
    unsigned short* Wt1 = (unsigned short*)ws;  ws += 65536;
    unsigned short* Wt2 = (unsigned short*)ws;  ws += 65536;
    int* cnt  = (int*)ws;  ws += (size_t)N * 4;
    int* cur  = (int*)ws;  ws += (size_t)N * 4;   // adjacent to cnt: one memset
    int* off  = (int*)ws;  ws += (size_t)(N + 1) * 4;
    int* bsum = (int*)ws;  ws += 1024;
    int* csr  = (int*)ws;

    int scanG = (N + 1023) / 1024;  // 98 for N=100000 (scan2 requires <=128)
    const int NSWEEP = 4;
    int range = (N + NSWEEP - 1) / NSWEEP;  // dst-range per fill_csr sweep

    // --- CSR build ---
    hipMemsetAsync(cnt, 0, (size_t)2 * N * 4, stream);      // cnt + cur
    count_deg<<<(E + 255) / 256, 256, 0, stream>>>(ei, E, cnt);
    scan1<<<scanG, 1024, 0, stream>>>(cnt, N, off, bsum);
    scan2<<<1, 128, 0, stream>>>(bsum, scanG, off + N);
    scan3<<<scanG, 1024, 0, stream>>>(off, N, bsum);
    fill_csr<<<dim3((E + 255) / 256, NSWEEP), 256, 0, stream>>>(ei, E, off, cur, csr, range);

    // --- weight prep (Wt[f][k]: k<128 = Wl, k>=128 = Wr) ---
    prep_weights<<<64, 256, 0, stream>>>(Wl1, Wr1, Wl2, Wr2, Wt1, Wt2);

    int aggGrid  = (N + 3) / 4;
    int gemmGrid = (N + 63) / 64;

    if (big) {
        cast_bf16<<<(N * DD / 4 + 255) / 256, 256, 0, stream>>>(x, xb, N * DD / 4);
        aggregate_bf<<<aggGrid, 256, 0, stream>>>(xb, off, csr, mean, N, nullptr);
        gemm_mfma<unsigned short, unsigned short><<<gemmGrid, 256, 0, stream>>>(
            mean, xb, Wt1, bl1, h, N, N, nullptr);
    } else {
        aggregate_f32<<<aggGrid, 256, 0, stream>>>(x, off, csr, mean, N);
        gemm_mfma<float, unsigned short><<<gemmGrid, 256, 0, stream>>>(
            mean, x, Wt1, bl1, h, N, N, nullptr);
    }
    aggregate_bf<<<aggGrid, 256, 0, stream>>>(h, off, csr, mean, N, org);
    gemm_mfma<unsigned short, float><<<gemmGrid, 256, 0, stream>>>(
        mean, h, Wt2, bl2, out, N, N, org);
}

// Round 7
// 466.032 us; speedup vs baseline: 1.8105x; 1.0056x over previous
//
#include <hip/hip_runtime.h>

#define NN 100000
#define DD 128

typedef __attribute__((ext_vector_type(8))) short bf16x8;
typedef __attribute__((ext_vector_type(4))) float f32x4;

__device__ __forceinline__ float bf2f(unsigned short u) {
    union { unsigned int i; float f; } v;
    v.i = ((unsigned int)u) << 16;
    return v.f;
}

__device__ __forceinline__ unsigned short f2bf(float f) {
    union { float f; unsigned int i; } v;
    v.f = f;
    unsigned int x = v.i;
    return (unsigned short)((x + 0x7FFFu + ((x >> 16) & 1u)) >> 16);
}

__device__ __forceinline__ float2 load2(const float* p, int i2) {
    return ((const float2*)p)[i2];
}

// 8 bf16 elements from bf16 or fp32 storage (for GEMM A staging)
__device__ __forceinline__ bf16x8 load8_bf(const unsigned short* p) {
    return *((const bf16x8*)p);
}
__device__ __forceinline__ bf16x8 load8_bf(const float* p) {
    float4 a = ((const float4*)p)[0];
    float4 b = ((const float4*)p)[1];
    bf16x8 r;
    r[0] = (short)f2bf(a.x); r[1] = (short)f2bf(a.y);
    r[2] = (short)f2bf(a.z); r[3] = (short)f2bf(a.w);
    r[4] = (short)f2bf(b.x); r[5] = (short)f2bf(b.y);
    r[6] = (short)f2bf(b.z); r[7] = (short)f2bf(b.w);
    return r;
}

// int64 little-endian edges with values < 2^31 => odd int32 words all zero.
// Per-block detection: wave 0 checks 64 samples, shares via LDS.
__device__ __forceinline__ int block_is64(const int* __restrict__ ei) {
    __shared__ int is64_s;
    if (threadIdx.x < 64) {
        int ok = (ei[2 * threadIdx.x + 1] == 0);
        int all = __all(ok);
        if (threadIdx.x == 0) is64_s = all;
    }
    __syncthreads();
    return is64_s;
}

__global__ void count_deg(const int* __restrict__ ei, int E, int* __restrict__ cnt) {
    int is64 = block_is64(ei);
    int e = blockIdx.x * blockDim.x + threadIdx.x;
    if (e >= E) return;
    int d = is64 ? ei[2 * (E + e)] : ei[E + e];
    atomicAdd(&cnt[d], 1);
}

// ---- multi-block scan (3 passes) ----
__global__ void scan1(const int* __restrict__ cnt, int N, int* __restrict__ off,
                      int* __restrict__ bsum) {
    __shared__ int wsum[16];
    int i = blockIdx.x * 1024 + threadIdx.x;
    int lane = threadIdx.x & 63, wid = threadIdx.x >> 6;
    int v = (i < N) ? cnt[i] : 0;
    int s = v;
#pragma unroll
    for (int d = 1; d < 64; d <<= 1) {
        int t = __shfl_up(s, d, 64);
        if (lane >= d) s += t;
    }
    if (lane == 63) wsum[wid] = s;
    __syncthreads();
    int woff = 0;
#pragma unroll
    for (int w = 0; w < 16; w++) woff += (w < wid) ? wsum[w] : 0;
    if (i < N) off[i] = woff + s - v;   // block-local exclusive
    if (threadIdx.x == 1023) bsum[blockIdx.x] = woff + s;
}

__global__ void scan2(int* __restrict__ bsum, int G, int* __restrict__ offN) {
    __shared__ int w0sum;
    int lane = threadIdx.x & 63, wid = threadIdx.x >> 6;
    int v = (threadIdx.x < G) ? bsum[threadIdx.x] : 0;
    int s = v;
#pragma unroll
    for (int d = 1; d < 64; d <<= 1) {
        int t = __shfl_up(s, d, 64);
        if (lane >= d) s += t;
    }
    if (wid == 0 && lane == 63) w0sum = s;
    __syncthreads();
    int base = wid ? w0sum : 0;
    if (threadIdx.x < G) bsum[threadIdx.x] = base + s - v;  // exclusive
    if (threadIdx.x == G - 1) offN[0] = base + s;           // grand total
}

__global__ void scan3(int* __restrict__ off, int N, const int* __restrict__ bsum) {
    int i = blockIdx.x * 1024 + threadIdx.x;
    if (i < N) off[i] += bsum[blockIdx.x];
}

// XCD-partitioned CSR fill.
// Round-6 post-mortem: time-sweeping the dst-range did NOT kill write
// amplification (93 MB for 6.4 MB payload) because each 64 B csr line gets
// its 16 entries from edges scattered across the whole edge array -> written
// by blocks on all 8 XCDs -> 8 partially-dirty non-coherent L2 copies, each
// written back separately (~100k lines x 8 x 64 B ~ 51 MB + churn).
// Fix: range r = blockIdx.x & 7 -- consecutive blockIdx round-robin across
// XCDs (sanctioned %8 heuristic), so one dst-range is written by ONE XCD:
// every csr line dirtied in a single L2, fully filled before write-back.
// Coverage is structural (each range scans all edges): mapping changes only
// affect speed, never correctness.
__global__ void fill_csr(const int* __restrict__ ei, int E,
                         const int* __restrict__ off, int* __restrict__ cur,
                         int* __restrict__ csr, int range, int nrange) {
    int is64 = block_is64(ei);
    int r = blockIdx.x & (nrange - 1);
    int e = (blockIdx.x >> 3) * blockDim.x + threadIdx.x;
    if (e >= E) return;
    int d = is64 ? ei[2 * (E + e)] : ei[E + e];
    int lo = r * range;
    if (d < lo || d >= lo + range) return;
    int s = is64 ? ei[2 * e] : ei[e];
    int p = atomicAdd(&cur[d], 1);
    csr[off[d] + p] = s;
}

__global__ void cast_bf16(const float* __restrict__ in, unsigned short* __restrict__ out,
                          int n4) {
    int i = blockIdx.x * blockDim.x + threadIdx.x;
    if (i >= n4) return;
    float4 v = ((const float4*)in)[i];
    ushort4 o;
    o.x = f2bf(v.x); o.y = f2bf(v.y); o.z = f2bf(v.z); o.w = f2bf(v.w);
    ((ushort4*)out)[i] = o;
}

// All 4 weight transposes in one launch. Wt[f][koff+k] = bf16(W[k][f]).
// grid 64: blockIdx>>4 selects matrix, &15 selects 32x32 sub-tile.
__global__ void prep_weights(const float* __restrict__ Wl1, const float* __restrict__ Wr1,
                             const float* __restrict__ Wl2, const float* __restrict__ Wr2,
                             unsigned short* __restrict__ Wt1, unsigned short* __restrict__ Wt2) {
    __shared__ float t[32][33];
    int which = blockIdx.x >> 4;
    const float* W = (which == 0) ? Wl1 : (which == 1) ? Wr1 : (which == 2) ? Wl2 : Wr2;
    unsigned short* Wt = (which < 2) ? Wt1 : Wt2;
    int koff = (which & 1) * 128;
    int b = blockIdx.x & 15;
    int bx = b & 3, by = b >> 2;
    int c = threadIdx.x & 31, r8 = threadIdx.x >> 5;
#pragma unroll
    for (int i = 0; i < 4; i++) {
        int r = r8 + i * 8;
        t[r][c] = W[(by * 32 + r) * 128 + bx * 32 + c];
    }
    __syncthreads();
#pragma unroll
    for (int i = 0; i < 4; i++) {
        int r = r8 + i * 8;
        Wt[(bx * 32 + r) * 256 + koff + by * 32 + c] = f2bf(t[c][r]);
    }
}

// Fast aggregate (bf16 features): one wave per node.
// lane = (e = lane>>4: edge slot, q = lane&15: feature octet).
// Per iteration: 4 edges x 16 B/lane = 1 KB/wave in flight; unrolled x2 (8 edges).
// Cross-slot reduce: shfl_xor 16/32 at node end.
__global__ __launch_bounds__(256) void aggregate_bf(
    const unsigned short* __restrict__ feat,
    const int* __restrict__ off, const int* __restrict__ csr,
    unsigned short* __restrict__ mean, int N, const int* __restrict__ limp) {
    int lim = limp ? min(N, limp[0]) : N;
    int node = blockIdx.x * (blockDim.x >> 6) + (threadIdx.x >> 6);
    if (node >= lim) return;
    int lane = threadIdx.x & 63;
    int e = lane >> 4, q = lane & 15;
    int s0 = off[node], s1 = off[node + 1];

    float acc[8];
#pragma unroll
    for (int t = 0; t < 8; t++) acc[t] = 0.f;

    int j = s0 + e;
    // unrolled x2: issue both csr loads, then both feature loads, then accumulate
    while (j + 4 < s1) {
        int sa = csr[j];
        int sb = csr[j + 4];
        bf16x8 va = *((const bf16x8*)(feat + (size_t)sa * 128 + q * 8));
        bf16x8 vb = *((const bf16x8*)(feat + (size_t)sb * 128 + q * 8));
#pragma unroll
        for (int t = 0; t < 8; t++) acc[t] += bf2f((unsigned short)va[t]);
#pragma unroll
        for (int t = 0; t < 8; t++) acc[t] += bf2f((unsigned short)vb[t]);
        j += 8;
    }
    if (j < s1) {
        int sa = csr[j];
        bf16x8 va = *((const bf16x8*)(feat + (size_t)sa * 128 + q * 8));
#pragma unroll
        for (int t = 0; t < 8; t++) acc[t] += bf2f((unsigned short)va[t]);
    }

#pragma unroll
    for (int t = 0; t < 8; t++) {
        acc[t] += __shfl_xor(acc[t], 16, 64);
        acc[t] += __shfl_xor(acc[t], 32, 64);
    }

    int deg = s1 - s0;
    float inv = (deg > 0) ? (1.0f / (float)deg) : 0.0f;
    if (e == 0) {
        bf16x8 o;
#pragma unroll
        for (int t = 0; t < 8; t++) o[t] = (short)f2bf(acc[t] * inv);
        *((bf16x8*)(mean + (size_t)node * 128 + q * 8)) = o;
    }
}

// Fallback scalar aggregate for fp32 features (non-big path only)
__global__ void aggregate_f32(const float* __restrict__ feat,
                              const int* __restrict__ off, const int* __restrict__ csr,
                              unsigned short* __restrict__ mean, int N) {
    int node = blockIdx.x * (blockDim.x >> 6) + (threadIdx.x >> 6);
    if (node >= N) return;
    int lane = threadIdx.x & 63;
    int s0 = off[node], s1 = off[node + 1];
    float ax = 0.f, ay = 0.f;
    for (int j = s0; j < s1; j++) {
        int s = csr[j];
        float2 v = load2(feat, s * 64 + lane);
        ax += v.x; ay += v.y;
    }
    float inv = (s1 > s0) ? (1.0f / (float)(s1 - s0)) : 0.0f;
    unsigned int p = (unsigned int)f2bf(ax * inv) | ((unsigned int)f2bf(ay * inv) << 16);
    ((unsigned int*)mean)[node * 64 + lane] = p;
}

// out[n][f] = sum_k A1[n][k]*Wt[f][k] (k<128) + A2[n][k]*Wt[f][128+k] + bias[f]
// block: 256 thr = 4 waves in 2x2; block tile 64 M x 128 N; wave tile 32 M x 64 N.
// MFMA 16x16x32 bf16. A-frag: A[m=lane&15][k=quad*8+j]; B mirrored; D: col=lane&15,
// row=quad*4+reg (HW-verified layouts, learn_hip m89/m120).
template <typename TA2, typename TO>
__global__ __launch_bounds__(256) void gemm_mfma(
    const unsigned short* __restrict__ A1, const TA2* __restrict__ A2,
    const unsigned short* __restrict__ Wt, const float* __restrict__ bias,
    TO* __restrict__ out, int Arows, int Nlimit, const int* __restrict__ origp) {
    int lim = Nlimit;
    if (origp) lim = min(lim, origp[0]);
    int n0 = blockIdx.x * 64;
    if (n0 >= lim) return;

    __shared__ unsigned short A_lds[64 * 40];  // stride 40 bf16 = 80 B: 2-way (free)

    int tid = threadIdx.x;
    int lane = tid & 63;
    int wid = tid >> 6;
    int wm = wid >> 1, wn = wid & 1;
    int qd = lane >> 4, l16 = lane & 15;

    f32x4 acc[2][4];
#pragma unroll
    for (int a = 0; a < 2; a++)
#pragma unroll
        for (int b = 0; b < 4; b++) acc[a][b] = (f32x4){0.f, 0.f, 0.f, 0.f};

    int srow = tid >> 2, sq = tid & 3;   // staging: row 0..63, 16B quarter 0..3

    for (int ks = 0; ks < 8; ks++) {
        int phase = ks >> 2;             // 0: A1 (mean), 1: A2 (root)
        int kb = (ks & 3) * 32;          // k offset within the 128-wide A row
        __syncthreads();
        {
            int gn = n0 + srow;
            bf16x8 v = (bf16x8){0, 0, 0, 0, 0, 0, 0, 0};
            if (gn < Arows) {
                if (phase)
                    v = load8_bf(A2 + gn * 128 + kb + sq * 8);
                else
                    v = load8_bf(A1 + gn * 128 + kb + sq * 8);
            }
            *((bf16x8*)(A_lds + srow * 40 + sq * 8)) = v;
        }
        __syncthreads();

        bf16x8 afrag[2];
#pragma unroll
        for (int tm = 0; tm < 2; tm++)
            afrag[tm] = *((const bf16x8*)(A_lds + (wm * 32 + tm * 16 + l16) * 40 + qd * 8));
#pragma unroll
        for (int tn = 0; tn < 4; tn++) {
            int f = wn * 64 + tn * 16 + l16;
            bf16x8 bfrag = *((const bf16x8*)(Wt + f * 256 + ks * 32 + qd * 8));
            acc[0][tn] = __builtin_amdgcn_mfma_f32_16x16x32_bf16(afrag[0], bfrag, acc[0][tn], 0, 0, 0);
            acc[1][tn] = __builtin_amdgcn_mfma_f32_16x16x32_bf16(afrag[1], bfrag, acc[1][tn], 0, 0, 0);
        }
    }

#pragma unroll
    for (int tn = 0; tn < 4; tn++) {
        int f = wn * 64 + tn * 16 + l16;
        float bv = bias[f];
#pragma unroll
        for (int tm = 0; tm < 2; tm++) {
#pragma unroll
            for (int r = 0; r < 4; r++) {
                int n = n0 + wm * 32 + tm * 16 + qd * 4 + r;
                if (n < lim) {
                    float val = acc[tm][tn][r] + bv;
                    if constexpr (__is_same(TO, float))
                        out[n * 128 + f] = val;
                    else
                        out[n * 128 + f] = f2bf(val);
                }
            }
        }
    }
}

extern "C" void kernel_launch(void* const* d_in, const int* in_sizes, int n_in,
                              void* d_out, int out_size, void* d_ws, size_t ws_size,
                              hipStream_t stream) {
    const float* x   = (const float*)d_in[0];
    const int*   ei  = (const int*)d_in[1];
    const int*   org = (const int*)d_in[2];
    const float* Wl1 = (const float*)d_in[3];
    const float* bl1 = (const float*)d_in[4];
    const float* Wr1 = (const float*)d_in[5];
    const float* Wl2 = (const float*)d_in[6];
    const float* bl2 = (const float*)d_in[7];
    const float* Wr2 = (const float*)d_in[8];
    float* out = (float*)d_out;

    const int N = in_sizes[0] / DD;
    const int E = in_sizes[1] / 2;

    size_t szFeat = (size_t)N * DD * 2;          // bf16 feature matrix
    size_t szBase = 2 * szFeat                    // mean + h
                  + 2 * 65536                     // Wt1 + Wt2
                  + (size_t)N * 4 * 2             // cnt + cur
                  + (size_t)(N + 1) * 4           // off
                  + 1024                          // bsum
                  + (size_t)E * 4;                // csr
    bool big = ws_size >= szBase + szFeat + 4096; // room for bf16 x too?

    char* ws = (char*)d_ws;
    unsigned short* mean = (unsigned short*)ws;  ws += szFeat;
    unsigned short* h    = (unsigned short*)ws;  ws += szFeat;
    unsigned short* xb   = nullptr;
    if (big) { xb = (unsigned short*)ws; ws += szFeat; }
    unsigned short* Wt1 = (unsigned short*)ws;  ws += 65536;
    unsigned short* Wt2 = (unsigned short*)ws;  ws += 65536;
    int* cnt  = (int*)ws;  ws += (size_t)N * 4;
    int* cur  = (int*)ws;  ws += (size_t)N * 4;   // adjacent to cnt: one memset
    int* off  = (int*)ws;  ws += (size_t)(N + 1) * 4;
    int* bsum = (int*)ws;  ws += 1024;
    int* csr  = (int*)ws;

    int scanG = (N + 1023) / 1024;  // 98 for N=100000 (scan2 requires <=128)
    const int NRANGE = 8;                    // one dst-range per XCD
    int range = (N + NRANGE - 1) / NRANGE;   // 12500

    // --- CSR build ---
    hipMemsetAsync(cnt, 0, (size_t)2 * N * 4, stream);      // cnt + cur
    count_deg<<<(E + 255) / 256, 256, 0, stream>>>(ei, E, cnt);
    scan1<<<scanG, 1024, 0, stream>>>(cnt, N, off, bsum);
    scan2<<<1, 128, 0, stream>>>(bsum, scanG, off + N);
    scan3<<<scanG, 1024, 0, stream>>>(off, N, bsum);
    // grid: (edge-chunks x 8 ranges); consecutive blocks -> round-robin XCDs
    fill_csr<<<((E + 255) / 256) * NRANGE, 256, 0, stream>>>(ei, E, off, cur, csr,
                                                             range, NRANGE);

    // --- weight prep (Wt[f][k]: k<128 = Wl, k>=128 = Wr) ---
    prep_weights<<<64, 256, 0, stream>>>(Wl1, Wr1, Wl2, Wr2, Wt1, Wt2);

    int aggGrid  = (N + 3) / 4;
    int gemmGrid = (N + 63) / 64;

    if (big) {
        cast_bf16<<<(N * DD / 4 + 255) / 256, 256, 0, stream>>>(x, xb, N * DD / 4);
        aggregate_bf<<<aggGrid, 256, 0, stream>>>(xb, off, csr, mean, N, nullptr);
        gemm_mfma<unsigned short, unsigned short><<<gemmGrid, 256, 0, stream>>>(
            mean, xb, Wt1, bl1, h, N, N, nullptr);
    } else {
        aggregate_f32<<<aggGrid, 256, 0, stream>>>(x, off, csr, mean, N);
        gemm_mfma<float, unsigned short><<<gemmGrid, 256, 0, stream>>>(
            mean, x, Wt1, bl1, h, N, N, nullptr);
    }
    aggregate_bf<<<aggGrid, 256, 0, stream>>>(h, off, csr, mean, N, org);
    gemm_mfma<unsigned short, float><<<gemmGrid, 256, 0, stream>>>(
        mean, h, Wt2, bl2, out, N, N, org);
}